// Round 1
// baseline (371.930 us; speedup 1.0000x reference)
//
#include <hip/hip_runtime.h>
#include <hip/hip_fp16.h>
#include <hip/hip_cooperative_groups.h>

namespace cg = cooperative_groups;

#define NROW 512
#define NCOL 65536
#define NBLK 256
#define NTHR 1024

__device__ __forceinline__ float dot8(const float4& kraw, const float4& va, const float4& vb) {
  const __half2* hp = (const __half2*)&kraw;
  float2 k0 = __half22float2(hp[0]);
  float2 k1 = __half22float2(hp[1]);
  float2 k2 = __half22float2(hp[2]);
  float2 k3 = __half22float2(hp[3]);
  return k0.x*va.x + k0.y*va.y + k1.x*va.z + k1.y*va.w
       + k2.x*vb.x + k2.y*vb.y + k3.x*vb.z + k3.y*vb.w;
}

// One cooperative kernel does everything:
//  phase 0: Kh = (half)exp(-20*M); init u, err accumulators, out
//  loop:    colsum t = K^T u  -> (deferred err check) -> v = b/(t+eps)
//           rowdot r = K v    -> u = a/(r+eps)
//           exact reference semantics: err computed at cpt==1 and cpt==51
//           using the NEXT iteration's colsum (same value K^T u_new), break
//           BEFORE overwriting v so final (u,v) match the reference.
//  loss:    out = 100 * sum(u_i * K_ij * v_j * M_ij)
__global__ __launch_bounds__(NTHR, 1)
void sinkhorn_all(const float* __restrict__ M, float* __restrict__ out,
                  __half* __restrict__ Kh, float* __restrict__ u,
                  float* __restrict__ v, float* __restrict__ errAcc) {
  cg::grid_group grid = cg::this_grid();
  const int tid = threadIdx.x;
  const int bid = blockIdx.x;
  const int gid = bid * NTHR + tid;
  const int NT  = NBLK * NTHR;                 // 262144 threads

  const float am   = 1.0f / NROW;
  const float bm   = 1.0f / NCOL;
  const float EPSV = 1e-16f;

  __shared__ float sU[NROW];                   // 2 KB
  __shared__ float sRed[NTHR];                 // 4 KB

  // ---------------- phase 0: build Kh (fp16), init state ----------------
  {
    const float4* M4 = (const float4*)M;
    __half2* K2 = (__half2*)Kh;
    const int nchunk = NROW * NCOL / 4;        // 8,388,608
    for (int c = gid; c < nchunk; c += NT) {
      float4 mv = M4[c];
      __half2 h0 = __floats2half2_rn(__expf(-20.0f*mv.x), __expf(-20.0f*mv.y));
      __half2 h1 = __floats2half2_rn(__expf(-20.0f*mv.z), __expf(-20.0f*mv.w));
      K2[2*c]   = h0;
      K2[2*c+1] = h1;
    }
    if (gid < NROW) u[gid] = am;
    if (gid < 2)   errAcc[gid] = 0.0f;
    if (gid == 0)  out[0] = 0.0f;
  }
  grid.sync();

  // ---------------- Sinkhorn loop ----------------
  int cpt = 0, errIdx = 0;
  bool pending = false;                        // err check deferred to next colsum
  const int col  = (bid << 8) + (tid & 255);   // this thread's column (colsum phase)
  const int part = tid >> 8;                   // row-quarter 0..3

  while (true) {
    // stage u into LDS (grid.sync at loop end / phase0 protects reuse)
    for (int i = tid; i < NROW; i += NTHR) sU[i] = u[i];
    __syncthreads();

    // colsum partial: rows [part*128, part*128+128) of column `col`
    float acc = 0.0f;
    {
      const __half* Kc = Kh + (size_t)(part * 128) * NCOL + col;
      const int rbase = part * 128;
      #pragma unroll 8
      for (int r = 0; r < 128; ++r)
        acc = fmaf(__half2float(Kc[(size_t)r * NCOL]), sU[rbase + r], acc);
    }
    sRed[tid] = acc;
    __syncthreads();
    float t = 0.0f;                            // full colsum, valid for tid<256
    if (tid < 256) t = sRed[tid] + sRed[tid+256] + sRed[tid+512] + sRed[tid+768];

    if (pending) {
      // err = sum_j |v_j * (K^T u)_j - b|   (v is still the previous iter's v)
      float pe = (tid < 256) ? fabsf(v[col]*t - bm) : 0.0f;
      __syncthreads();                         // sRed free for reuse
      #pragma unroll
      for (int off = 32; off > 0; off >>= 1) pe += __shfl_down(pe, off, 64);
      if ((tid & 63) == 0) sRed[tid >> 6] = pe;
      __syncthreads();
      if (tid == 0) {
        float bs = 0.0f;
        #pragma unroll
        for (int w = 0; w < 16; ++w) bs += sRed[w];
        atomicAdd(&errAcc[errIdx], bs);
      }
      grid.sync();
      float err = errAcc[errIdx];
      errIdx++;
      pending = false;
      if (err <= 0.005f) break;                // uniform decision; v,u untouched
      __syncthreads();
    }

    if (tid < 256) v[col] = bm / (t + EPSV);
    grid.sync();

    // rowdot: this block handles rows 2*bid and 2*bid+1
    float racc0 = 0.0f, racc1 = 0.0f;
    {
      const int row0 = bid << 1;
      const float4* K40 = (const float4*)(Kh + (size_t)row0 * NCOL);
      const float4* K41 = (const float4*)(Kh + (size_t)(row0+1) * NCOL);
      const float4* V4  = (const float4*)v;
      #pragma unroll
      for (int k = 0; k < 8; ++k) {
        const int c = (k << 10) + tid;         // chunk of 8 halves
        float4 va = V4[2*c], vb = V4[2*c+1];
        float4 kr0 = K40[c];
        float4 kr1 = K41[c];
        racc0 += dot8(kr0, va, vb);
        racc1 += dot8(kr1, va, vb);
      }
    }
    #pragma unroll
    for (int off = 32; off > 0; off >>= 1) {
      racc0 += __shfl_down(racc0, off, 64);
      racc1 += __shfl_down(racc1, off, 64);
    }
    __syncthreads();
    if ((tid & 63) == 0) { sRed[tid >> 6] = racc0; sRed[16 + (tid >> 6)] = racc1; }
    __syncthreads();
    if (tid < 2) {
      float bs = 0.0f;
      #pragma unroll
      for (int w = 0; w < 16; ++w) bs += sRed[tid*16 + w];
      u[(bid << 1) + tid] = am / (bs + EPSV);
    }
    grid.sync();

    cpt++;
    pending = ((cpt % 50) == 1);               // checks fire at cpt==1 and cpt==51
    if (cpt >= 100) break;
  }

  // ---------------- loss: 100 * sum(u_i K_ij v_j M_ij) ----------------
  {
    const float4*  M4 = (const float4*)M;
    const __half2* K2 = (const __half2*)Kh;
    const float4*  V4 = (const float4*)v;
    float lacc = 0.0f;
    const int nchunk = NROW * NCOL / 4;
    for (int c = gid; c < nchunk; c += NT) {
      float4 mv = M4[c];
      float2 k0 = __half22float2(K2[2*c]);
      float2 k1 = __half22float2(K2[2*c+1]);
      const int i  = c >> 14;                  // NCOL/4 = 16384 chunks per row
      const int j4 = c & 16383;
      float ui = u[i];
      float4 vv = V4[j4];
      lacc += ui * (k0.x*vv.x*mv.x + k0.y*vv.y*mv.y + k1.x*vv.z*mv.z + k1.y*vv.w*mv.w);
    }
    #pragma unroll
    for (int off = 32; off > 0; off >>= 1) lacc += __shfl_down(lacc, off, 64);
    __syncthreads();
    if ((tid & 63) == 0) sRed[tid >> 6] = lacc;
    __syncthreads();
    if (tid == 0) {
      float bs = 0.0f;
      #pragma unroll
      for (int w = 0; w < 16; ++w) bs += sRed[w];
      atomicAdd(out, bs * 100.0f);
    }
  }
}

extern "C" void kernel_launch(void* const* d_in, const int* in_sizes, int n_in,
                              void* d_out, int out_size, void* d_ws, size_t ws_size,
                              hipStream_t stream) {
  const float* M = (const float*)d_in[0];
  float* out = (float*)d_out;

  const size_t szK  = (size_t)NROW * NCOL * sizeof(__half);  // 67,108,864 B
  const size_t offU = szK;
  const size_t offV = offU + 4096;
  const size_t offE = offV + (size_t)NCOL * sizeof(float);
  const size_t need = offE + 4096;
  if (ws_size < need) return;  // insufficient scratch -> loud validation failure

  char* ws = (char*)d_ws;
  __half* Kh  = (__half*)(ws);
  float*  u   = (float*)(ws + offU);
  float*  v   = (float*)(ws + offV);
  float*  eA  = (float*)(ws + offE);

  void* args[] = { (void*)&M, (void*)&out, (void*)&Kh, (void*)&u, (void*)&v, (void*)&eA };
  hipLaunchCooperativeKernel((void*)sinkhorn_all, dim3(NBLK), dim3(NTHR), args, 0, stream);
}

// Round 2
// 355.023 us; speedup vs baseline: 1.0476x; 1.0476x over previous
//
#include <hip/hip_runtime.h>
#include <hip/hip_fp16.h>
#include <hip/hip_cooperative_groups.h>

namespace cg = cooperative_groups;

#define NROW 512
#define NCOL 65536
#define NBLK 256
#define NTHR 1024
#define NT   (NBLK * NTHR)

__device__ __forceinline__ float dot8(const float4& kraw, const float4& va, const float4& vb) {
  const __half2* hp = (const __half2*)&kraw;
  float2 k0 = __half22float2(hp[0]);
  float2 k1 = __half22float2(hp[1]);
  float2 k2 = __half22float2(hp[2]);
  float2 k3 = __half22float2(hp[3]);
  return k0.x*va.x + k0.y*va.y + k1.x*va.z + k1.y*va.w
       + k2.x*vb.x + k2.y*vb.y + k3.x*vb.z + k3.y*vb.w;
}

// Single cooperative kernel:
//  phase0: Kh = (half)exp(-20*M), FUSED colsum t0 = K^T u0 (u0 uniform) -> v1.
//          (saves one full K pass vs separate first colsum)
//  loop:   rowdot u_k = a/(K v_k); colsum t_k = K^T u_k;
//          err check at cpt==1,51 (reference semantics: break keeps u_k, v_k);
//          v_{k+1} = b/(t_k+eps).
//  loss:   100 * sum(u_i K_ij v_j M_ij) with M recovered as -ln(Kh)/20
//          (eliminates the 134 MB HBM re-read of M; K==0 entries contribute 0)
__global__ __launch_bounds__(NTHR)
void sinkhorn_all(const float* __restrict__ M, float* __restrict__ out,
                  __half* __restrict__ Kh, float* __restrict__ u,
                  float* __restrict__ v, float* __restrict__ errAcc) {
  cg::grid_group grid = cg::this_grid();
  const int tid = threadIdx.x;
  const int bid = blockIdx.x;
  const int gid = bid * NTHR + tid;

  const float am   = 1.0f / NROW;
  const float bm   = 1.0f / NCOL;
  const float EPSV = 1e-16f;

  __shared__ float sCol[32 * 256];   // 32 KB: [row-part][col-in-block]
  __shared__ float sU[NROW];         // 2 KB
  __shared__ float sRed[32];

  const int chunk = tid & 31;        // 32 column-chunks of 8 cols
  const int part  = tid >> 5;        // 32 row-parts of 16 rows
  const int col0  = (bid << 8) + (chunk << 3);
  const int r0    = part << 4;
  const int myCol = (bid << 8) + tid;          // valid for tid<256

  // ---------- phase 0: build Kh + fused first colsum -> v1 ----------
  {
    float cs0=0,cs1=0,cs2=0,cs3=0,cs4=0,cs5=0,cs6=0,cs7=0;
    for (int r = r0; r < r0 + 16; ++r) {
      const float4* Mrow = (const float4*)(M + (size_t)r * NCOL + col0);
      float4 m0 = Mrow[0], m1 = Mrow[1];
      __half2 hv[4];
      hv[0] = __floats2half2_rn(__expf(-20.f*m0.x), __expf(-20.f*m0.y));
      hv[1] = __floats2half2_rn(__expf(-20.f*m0.z), __expf(-20.f*m0.w));
      hv[2] = __floats2half2_rn(__expf(-20.f*m1.x), __expf(-20.f*m1.y));
      hv[3] = __floats2half2_rn(__expf(-20.f*m1.z), __expf(-20.f*m1.w));
      *(float4*)(Kh + (size_t)r * NCOL + col0) = *(const float4*)hv;
      // accumulate the fp16-rounded values so t0 is self-consistent with Kh
      float2 f0 = __half22float2(hv[0]), f1 = __half22float2(hv[1]);
      float2 f2 = __half22float2(hv[2]), f3 = __half22float2(hv[3]);
      cs0 += f0.x; cs1 += f0.y; cs2 += f1.x; cs3 += f1.y;
      cs4 += f2.x; cs5 += f2.y; cs6 += f3.x; cs7 += f3.y;
    }
    float* sc = sCol + part * 256 + (chunk << 3);
    sc[0]=cs0; sc[1]=cs1; sc[2]=cs2; sc[3]=cs3;
    sc[4]=cs4; sc[5]=cs5; sc[6]=cs6; sc[7]=cs7;
    if (gid < NROW) u[gid] = am;
    if (gid < 2)    errAcc[gid] = 0.0f;
    if (gid == 0)   out[0] = 0.0f;
    __syncthreads();
    if (tid < 256) {
      float t = 0.0f;
      #pragma unroll
      for (int p = 0; p < 32; ++p) t += sCol[p * 256 + tid];
      v[myCol] = bm / (t * am + EPSV);         // v1 = b/(K^T u0 + eps)
    }
  }
  grid.sync();

  // ---------- Sinkhorn loop ----------
  int cpt = 0, errIdx = 0;
  const int row0 = bid << 1;
  while (true) {
    // rowdot: u_{cpt+1} = a / (K v + eps); block handles rows row0, row0+1
    float ra = 0.0f, rb = 0.0f;
    {
      const float4* K40 = (const float4*)(Kh + (size_t)row0 * NCOL);
      const float4* K41 = (const float4*)(Kh + (size_t)(row0 + 1) * NCOL);
      const float4* V4  = (const float4*)v;
      #pragma unroll
      for (int kk = 0; kk < 8; ++kk) {
        const int c = (kk << 10) + tid;
        float4 va = V4[2*c], vb = V4[2*c + 1];
        ra += dot8(K40[c], va, vb);
        rb += dot8(K41[c], va, vb);
      }
    }
    #pragma unroll
    for (int off = 32; off > 0; off >>= 1) {
      ra += __shfl_down(ra, off, 64);
      rb += __shfl_down(rb, off, 64);
    }
    if ((tid & 63) == 0) { sRed[tid >> 6] = ra; sRed[16 + (tid >> 6)] = rb; }
    __syncthreads();
    if (tid < 2) {
      float s = 0.0f;
      #pragma unroll
      for (int w = 0; w < 16; ++w) s += sRed[tid * 16 + w];
      u[row0 + tid] = am / (s + EPSV);
    }
    grid.sync();

    cpt++;
    if (cpt >= 100) break;                      // final state: u_100, v_100
    const bool pending = ((cpt % 50) == 1);     // err checks at cpt==1, 51

    // colsum: t = K^T u
    if (tid < NROW) sU[tid] = u[tid];
    __syncthreads();
    float cs0=0,cs1=0,cs2=0,cs3=0,cs4=0,cs5=0,cs6=0,cs7=0;
    for (int r = r0; r < r0 + 16; ++r) {
      float4 kraw = *(const float4*)(Kh + (size_t)r * NCOL + col0);
      const __half2* hp = (const __half2*)&kraw;
      float us = sU[r];
      float2 f0 = __half22float2(hp[0]), f1 = __half22float2(hp[1]);
      float2 f2 = __half22float2(hp[2]), f3 = __half22float2(hp[3]);
      cs0 = fmaf(f0.x, us, cs0); cs1 = fmaf(f0.y, us, cs1);
      cs2 = fmaf(f1.x, us, cs2); cs3 = fmaf(f1.y, us, cs3);
      cs4 = fmaf(f2.x, us, cs4); cs5 = fmaf(f2.y, us, cs5);
      cs6 = fmaf(f3.x, us, cs6); cs7 = fmaf(f3.y, us, cs7);
    }
    {
      float* sc = sCol + part * 256 + (chunk << 3);
      sc[0]=cs0; sc[1]=cs1; sc[2]=cs2; sc[3]=cs3;
      sc[4]=cs4; sc[5]=cs5; sc[6]=cs6; sc[7]=cs7;
    }
    __syncthreads();
    float t = 0.0f;
    if (tid < 256) {
      #pragma unroll
      for (int p = 0; p < 32; ++p) t += sCol[p * 256 + tid];
    }

    if (pending) {
      // err = sum_j |v_j * (K^T u)_j - b|  with the CURRENT v (pre-update)
      float pe = (tid < 256) ? fabsf(v[myCol] * t - bm) : 0.0f;
      #pragma unroll
      for (int off = 32; off > 0; off >>= 1) pe += __shfl_down(pe, off, 64);
      if ((tid & 63) == 0) sRed[tid >> 6] = pe;
      __syncthreads();
      if (tid == 0) {
        float s = 0.0f;
        #pragma unroll
        for (int w = 0; w < 16; ++w) s += sRed[w];
        atomicAdd(&errAcc[errIdx], s);
      }
      grid.sync();
      float err = errAcc[errIdx];
      errIdx++;
      if (err <= 0.005f) break;                 // keep u_cpt, v_cpt
      __syncthreads();
    }

    if (tid < 256) v[myCol] = bm / (t + EPSV);
    grid.sync();
  }

  // ---------- loss: 100 * sum(u_i K_ij v_j M_ij), M = -ln(K)/20 ----------
  {
    const float4* K8 = (const float4*)Kh;       // 8 halves per load
    const float4* V4 = (const float4*)v;
    float lacc = 0.0f;
    const int nch = NROW * NCOL / 8;            // 4,194,304
    for (int c = gid; c < nch; c += NT) {
      float4 kraw = K8[c];
      const __half2* hp = (const __half2*)&kraw;
      float2 f0 = __half22float2(hp[0]), f1 = __half22float2(hp[1]);
      float2 f2 = __half22float2(hp[2]), f3 = __half22float2(hp[3]);
      const int row = c >> 13;                  // NCOL/8 = 8192 chunks per row
      const int cc  = c & 8191;
      float ui = u[row];
      float4 va = V4[2*cc], vb = V4[2*cc + 1];
      // m = -ln(k)/20; k==0 entries contribute exactly 0 (k * finite)
      float s =
        f0.x * va.x * __logf(fmaxf(f0.x, 1e-12f)) +
        f0.y * va.y * __logf(fmaxf(f0.y, 1e-12f)) +
        f1.x * va.z * __logf(fmaxf(f1.x, 1e-12f)) +
        f1.y * va.w * __logf(fmaxf(f1.y, 1e-12f)) +
        f2.x * vb.x * __logf(fmaxf(f2.x, 1e-12f)) +
        f2.y * vb.y * __logf(fmaxf(f2.y, 1e-12f)) +
        f3.x * vb.z * __logf(fmaxf(f3.x, 1e-12f)) +
        f3.y * vb.w * __logf(fmaxf(f3.y, 1e-12f));
      lacc = fmaf(ui, s, lacc);
    }
    lacc *= -0.05f;                             // the -1/20 factor
    #pragma unroll
    for (int off = 32; off > 0; off >>= 1) lacc += __shfl_down(lacc, off, 64);
    if ((tid & 63) == 0) sRed[tid >> 6] = lacc;
    __syncthreads();
    if (tid == 0) {
      float s = 0.0f;
      #pragma unroll
      for (int w = 0; w < 16; ++w) s += sRed[w];
      atomicAdd(out, s * 100.0f);
    }
  }
}

extern "C" void kernel_launch(void* const* d_in, const int* in_sizes, int n_in,
                              void* d_out, int out_size, void* d_ws, size_t ws_size,
                              hipStream_t stream) {
  const float* M = (const float*)d_in[0];
  float* out = (float*)d_out;

  const size_t szK  = (size_t)NROW * NCOL * sizeof(__half);  // 67,108,864 B
  const size_t offU = szK;
  const size_t offV = offU + 4096;
  const size_t offE = offV + (size_t)NCOL * sizeof(float);
  const size_t need = offE + 4096;
  if (ws_size < need) return;

  char* ws = (char*)d_ws;
  __half* Kh = (__half*)(ws);
  float*  u  = (float*)(ws + offU);
  float*  v  = (float*)(ws + offV);
  float*  eA = (float*)(ws + offE);

  void* args[] = { (void*)&M, (void*)&out, (void*)&Kh, (void*)&u, (void*)&v, (void*)&eA };
  hipLaunchCooperativeKernel((void*)sinkhorn_all, dim3(NBLK), dim3(NTHR), args, 0, stream);
}